// Round 7
// baseline (353.529 us; speedup 1.0000x reference)
//
#include <hip/hip_runtime.h>
#include <hip/hip_bf16.h>
#include <math.h>

#define NF 128   // IN_F == HID == 128

typedef __bf16 bf16x8 __attribute__((ext_vector_type(8)));
typedef unsigned short ushort8 __attribute__((ext_vector_type(8)));
typedef float f32x4 __attribute__((ext_vector_type(4)));
typedef _Float16 half8 __attribute__((ext_vector_type(8)));
typedef _Float16 half4 __attribute__((ext_vector_type(4)));

static inline int ceil_div(int a, int b) { return (a + b - 1) / b; }

// ================= CSR build: two-level multisplit counting sort =================
// bucket = dst >> 8 (256 nodes per bucket). TILE = 4096 edges per block.

__global__ __launch_bounds__(256) void bucket_hist_kernel(const int* __restrict__ dst,
                                                          int* __restrict__ counts,
                                                          int e, int nblk, int nbuck) {
  __shared__ int h[256];
  int t = threadIdx.x, blk = blockIdx.x;
  h[t] = 0;
  __syncthreads();
  int base = blk * 4096;
#pragma unroll
  for (int k = 0; k < 16; ++k) {
    int i = base + k * 256 + t;
    if (i < e) atomicAdd(&h[dst[i] >> 8], 1);
  }
  __syncthreads();
  for (int b = t; b < nbuck; b += 256) counts[b * nblk + blk] = h[b];
}

__global__ __launch_bounds__(256) void bucket_scan_rows_kernel(int* __restrict__ counts,
                                                               int* __restrict__ btot,
                                                               int nblk) {
  __shared__ int sh[256];
  int b = blockIdx.x, t = threadIdx.x;
  int* row = counts + (size_t)b * nblk;
  int carry = 0;
  for (int base = 0; base < nblk; base += 256) {
    int v = (base + t < nblk) ? row[base + t] : 0;
    sh[t] = v;
    __syncthreads();
    for (int off = 1; off < 256; off <<= 1) {
      int add = (t >= off) ? sh[t - off] : 0;
      __syncthreads();
      sh[t] += add;
      __syncthreads();
    }
    if (base + t < nblk) row[base + t] = carry + sh[t] - v;
    carry += sh[255];
    __syncthreads();
  }
  if (t == 0) btot[b] = carry;
}

__global__ __launch_bounds__(256) void bucket_base_kernel(const int* __restrict__ btot,
                                                          int* __restrict__ bbase,
                                                          int nbuck, int e) {
  __shared__ int sh[256];
  __shared__ int carry;
  int t = threadIdx.x;
  if (t == 0) carry = 0;
  __syncthreads();
  for (int base = 0; base < nbuck; base += 256) {
    int v = (base + t < nbuck) ? btot[base + t] : 0;
    sh[t] = v;
    __syncthreads();
    for (int off = 1; off < 256; off <<= 1) {
      int add = (t >= off) ? sh[t - off] : 0;
      __syncthreads();
      sh[t] += add;
      __syncthreads();
    }
    if (base + t < nbuck) bbase[base + t] = carry + sh[t] - v;
    __syncthreads();
    if (t == 0) carry += sh[255];
    __syncthreads();
  }
  if (t == 0) bbase[nbuck] = e;
}

__global__ __launch_bounds__(256) void bucket_bin_kernel(const int* __restrict__ src,
                                                         const int* __restrict__ dst,
                                                         const int* __restrict__ counts,
                                                         const int* __restrict__ bbase,
                                                         int2* __restrict__ binned,
                                                         int e, int nblk, int nbuck) {
  __shared__ int cur[256];
  int t = threadIdx.x, blk = blockIdx.x;
  for (int b = t; b < nbuck; b += 256) cur[b] = counts[b * nblk + blk] + bbase[b];
  __syncthreads();
  int base = blk * 4096;
#pragma unroll
  for (int k = 0; k < 16; ++k) {
    int i = base + k * 256 + t;
    if (i < e) {
      int d = dst[i];
      int pos = atomicAdd(&cur[d >> 8], 1);
      binned[pos] = make_int2(src[i], d);
    }
  }
}

__global__ __launch_bounds__(256) void bucket_finalize_kernel(const int2* __restrict__ binned,
                                                              const int* __restrict__ bbase,
                                                              int* __restrict__ offsets,
                                                              int* __restrict__ csr,
                                                              float* __restrict__ dinv,
                                                              int n, int e, int nbuck) {
  __shared__ int deg[256];
  __shared__ int offs[256];
  __shared__ int cur[256];
  int b = blockIdx.x, t = threadIdx.x;
  int ebeg = bbase[b];
  int eend = bbase[b + 1];
  deg[t] = 0;
  __syncthreads();
  for (int j = ebeg + t; j < eend; j += 256) atomicAdd(&deg[binned[j].y & 255], 1);
  __syncthreads();
  int v = deg[t];
  offs[t] = v;
  __syncthreads();
  for (int off = 1; off < 256; off <<= 1) {
    int add = (t >= off) ? offs[t - off] : 0;
    __syncthreads();
    offs[t] += add;
    __syncthreads();
  }
  int excl = offs[t] - v;
  cur[t] = excl;
  int node = b * 256 + t;
  if (node < n) {
    offsets[node] = ebeg + excl;
    float d = (float)(v > 1 ? v : 1);
    dinv[node] = rsqrtf(d);
  }
  if (b == nbuck - 1 && t == 0) offsets[n] = e;
  __syncthreads();
  for (int j = ebeg + t; j < eend; j += 256) {
    int2 pr = binned[j];
    int pos = atomicAdd(&cur[pr.y & 255], 1);
    csr[ebeg + pos] = pr.x;
  }
}

// ---------------- scale16: out16[r][c] = fp16(x[r][c] * dinv[r]) ----------------
__global__ void scale16_kernel(const float* __restrict__ x, const float* __restrict__ dinv,
                               _Float16* __restrict__ out16, int n) {
  int i = blockIdx.x * 256 + threadIdx.x;   // float4 index, 32 per row
  if (i < n * (NF / 4)) {
    int row = i >> 5;
    float4 v = ((const float4*)x)[i];
    float d = dinv[row];
    half4 h;
    h[0] = (_Float16)(v.x * d); h[1] = (_Float16)(v.y * d);
    h[2] = (_Float16)(v.z * d); h[3] = (_Float16)(v.w * d);
    ((half4*)out16)[i] = h;
  }
}

// ---------------- SpMV (fp16 pre-scaled gather source) ----------------
__global__ __launch_bounds__(256) void spmv_kernel(
    const _Float16* __restrict__ xs16, const float* __restrict__ dinv,
    const int* __restrict__ offsets, const int* __restrict__ csr,
    const float* __restrict__ z, float a, float bz,
    float* __restrict__ out, _Float16* __restrict__ outs16, int n) {
  int w = threadIdx.x >> 6, lane = threadIdx.x & 63;
  int node = blockIdx.x * 4 + w;
  if (node >= n) return;
  int beg = __builtin_amdgcn_readfirstlane(offsets[node]);
  int end = __builtin_amdgcn_readfirstlane(offsets[node + 1]);
  int eh = lane >> 4;        // which edge of the quad (0..3)
  int cq = lane & 15;        // half8 slot within the 128-half row

  float acc[8];
#pragma unroll
  for (int j = 0; j < 8; ++j) acc[j] = 0.f;

  int e2 = beg;
  for (; e2 + 8 <= end; e2 += 8) {
    int s0 = csr[e2 + eh];
    int s1 = csr[e2 + 4 + eh];
    half8 g0 = ((const half8*)(xs16 + (size_t)s0 * NF))[cq];
    half8 g1 = ((const half8*)(xs16 + (size_t)s1 * NF))[cq];
#pragma unroll
    for (int j = 0; j < 8; ++j) acc[j] += (float)g0[j];
#pragma unroll
    for (int j = 0; j < 8; ++j) acc[j] += (float)g1[j];
  }
  for (; e2 + 4 <= end; e2 += 4) {
    int s0 = csr[e2 + eh];
    half8 g0 = ((const half8*)(xs16 + (size_t)s0 * NF))[cq];
#pragma unroll
    for (int j = 0; j < 8; ++j) acc[j] += (float)g0[j];
  }
  int rem = end - e2;
  if (eh < rem) {
    int s0 = csr[e2 + eh];
    half8 g0 = ((const half8*)(xs16 + (size_t)s0 * NF))[cq];
#pragma unroll
    for (int j = 0; j < 8; ++j) acc[j] += (float)g0[j];
  }
#pragma unroll
  for (int j = 0; j < 8; ++j) {
    acc[j] += __shfl_xor(acc[j], 16);
    acc[j] += __shfl_xor(acc[j], 32);
  }
  if (eh == 0) {
    float dv = dinv[node];
    float v[8];
#pragma unroll
    for (int j = 0; j < 8; ++j) v[j] = a * dv * acc[j];
    if (z) {
      const f32x4* zp = (const f32x4*)(z + (size_t)node * NF + cq * 8);
      f32x4 z0 = zp[0], z1 = zp[1];
#pragma unroll
      for (int j = 0; j < 4; ++j) { v[j] += bz * z0[j]; v[4 + j] += bz * z1[j]; }
    }
    f32x4 o0, o1;
#pragma unroll
    for (int j = 0; j < 4; ++j) { o0[j] = v[j]; o1[j] = v[4 + j]; }
    f32x4* op = (f32x4*)(out + (size_t)node * NF + cq * 8);
    op[0] = o0; op[1] = o1;
    if (outs16) {
      half8 hv;
#pragma unroll
      for (int j = 0; j < 8; ++j) hv[j] = (_Float16)(v[j] * dv);
      *(half8*)(outs16 + (size_t)node * NF + cq * 8) = hv;
    }
  }
}

// ---------------- W pre-split + frag-pack ----------------
__device__ __forceinline__ void pack_one(const float* __restrict__ W, ushort8* __restrict__ Wp,
                                         int f, int NT, int K) {
  int lane = f & 63;
  int hl = (f >> 6) & 1;
  int rest = f >> 7;
  int nt = rest % NT;
  int kunit = rest / NT;
  int nrow = nt * 16 + (lane & 15);
  int k0 = kunit * 32 + (lane >> 4) * 8;
  const float* srcp = W + (size_t)nrow * K + k0;
  ushort8 v;
#pragma unroll
  for (int j = 0; j < 8; ++j) {
    float x = srcp[j];
    __bf16 h = (__bf16)x;
    if (hl) h = (__bf16)(x - (float)h);
    v[j] = __builtin_bit_cast(unsigned short, h);
  }
  Wp[f] = v;
}

__global__ void pack_all_kernel(const float* __restrict__ W1, ushort8* __restrict__ P1,
                                const float* __restrict__ W3, ushort8* __restrict__ P3,
                                const float* __restrict__ Wm1, ushort8* __restrict__ PM1,
                                const float* __restrict__ Wm2, ushort8* __restrict__ PM2) {
  int f = blockIdx.x * 256 + threadIdx.x;
  if (f < 12288) pack_one(W1, P1, f, 8, 384);
  else if (f < 24576) pack_one(W3, P3, f - 12288, 8, 384);
  else if (f < 28672) pack_one(Wm1, PM1, f - 24576, 8, 128);
  else if (f < 30720) pack_one(Wm2, PM2, f - 28672, 4, 128);
}

// ================= split-bf16 MFMA GEMM machinery =================
// LDS A-layout: AHI/ALO [64 rows][16 frags] bf16x8, frag slot XOR-swizzled by row&15.
// Staging: full 128-k per part, register-prefetched one part ahead.

// scatter one f32 value into the split-bf16 LDS A-layout (b16 writes)
__device__ __forceinline__ void lds_put_split(unsigned short* AH, unsigned short* AL,
                                              int row, int col, float v) {
  __bf16 hh = (__bf16)v;
  __bf16 ll = (__bf16)(v - (float)hh);
  int off = row * 128 + ((((col >> 3) ^ (row & 15))) << 3) + (col & 7);
  AH[off] = __builtin_bit_cast(unsigned short, hh);
  AL[off] = __builtin_bit_cast(unsigned short, ll);
}

// convert 8 f32 (two float4) -> hi/lo bf16x8 and store as float4 pair
__device__ __forceinline__ void cvt_frag(const float4& a, const float4& b,
                                         float4* AHI, float4* ALO, int idx) {
  float xv[8] = {a.x, a.y, a.z, a.w, b.x, b.y, b.z, b.w};
  ushort8 hi, lo;
#pragma unroll
  for (int j = 0; j < 8; ++j) {
    __bf16 hh = (__bf16)xv[j];
    __bf16 ll = (__bf16)(xv[j] - (float)hh);
    hi[j] = __builtin_bit_cast(unsigned short, hh);
    lo[j] = __builtin_bit_cast(unsigned short, ll);
  }
  AHI[idx] = __builtin_bit_cast(float4, hi);
  ALO[idx] = __builtin_bit_cast(float4, lo);
}

// one 64-row x NC x 32k MFMA pass (3 split-bf16 MFMAs per tile)
template<int NT, int NT2>
__device__ __forceinline__ void gemm_step(const float4* AHI, const float4* ALO,
                                          const ushort8* __restrict__ Wp, int kunit,
                                          int lane, int wm, int wn, f32x4 (*acc)[NT2]) {
  bf16x8 ah[2], al[2];
#pragma unroll
  for (int mt = 0; mt < 2; ++mt) {
    int arow = wm * 32 + mt * 16 + (lane & 15);
    int fc = (kunit & 3) * 4 + (lane >> 4);
    int idx = arow * 16 + (fc ^ (arow & 15));
    ah[mt] = __builtin_bit_cast(bf16x8, AHI[idx]);
    al[mt] = __builtin_bit_cast(bf16x8, ALO[idx]);
  }
#pragma unroll
  for (int j = 0; j < NT2; ++j) {
    int nt = wn * NT2 + j;
    const ushort8* bp = Wp + (size_t)(kunit * NT + nt) * 2 * 64 + lane;
    bf16x8 bh = __builtin_bit_cast(bf16x8, bp[0]);
    bf16x8 bl = __builtin_bit_cast(bf16x8, bp[64]);
#pragma unroll
    for (int mt = 0; mt < 2; ++mt) {
      acc[mt][j] = __builtin_amdgcn_mfma_f32_16x16x32_bf16(ah[mt], bh, acc[mt][j], 0, 0, 0);
      acc[mt][j] = __builtin_amdgcn_mfma_f32_16x16x32_bf16(ah[mt], bl, acc[mt][j], 0, 0, 0);
      acc[mt][j] = __builtin_amdgcn_mfma_f32_16x16x32_bf16(al[mt], bh, acc[mt][j], 0, 0, 0);
    }
  }
}

// ---------------- conv1 GEMM: X = relu([F,T1,T2] @ W1^T + b1) ----------------
__global__ __launch_bounds__(256) void mfma_gemm3_kernel(
    const float* __restrict__ X0, const float* __restrict__ X1, const float* __restrict__ X2,
    const ushort8* __restrict__ Wp, const float* __restrict__ bias,
    float* __restrict__ out, int n) {
  __shared__ float4 AHI[1024];   // 64 rows x 16 frags
  __shared__ float4 ALO[1024];

  int tid = threadIdx.x;
  int lane = tid & 63, wid = tid >> 6;
  int wm = wid >> 1, wn = wid & 1;
  int r0 = blockIdx.x * 64;

  f32x4 acc[2][4];
#pragma unroll
  for (int mt = 0; mt < 2; ++mt)
#pragma unroll
    for (int j = 0; j < 4; ++j) acc[mt][j] = (f32x4)0.f;

  const float* Xarr[3] = {X0, X1, X2};
  float4 pa0[4], pa1[4];
  // prologue: issue part-0 loads
#pragma unroll
  for (int h = 0; h < 4; ++h) {
    int f = tid + h * 256, row = f >> 4, fc = f & 15, grow = r0 + row;
    float4 z = make_float4(0.f, 0.f, 0.f, 0.f);
    pa0[h] = z; pa1[h] = z;
    if (grow < n) {
      const float4* s = (const float4*)(X0 + (size_t)grow * NF + fc * 8);
      pa0[h] = s[0]; pa1[h] = s[1];
    }
  }
#pragma unroll
  for (int p = 0; p < 3; ++p) {
    // convert current prefetch regs -> LDS
#pragma unroll
    for (int h = 0; h < 4; ++h) {
      int f = tid + h * 256, row = f >> 4, fc = f & 15;
      cvt_frag(pa0[h], pa1[h], AHI, ALO, row * 16 + (fc ^ (row & 15)));
    }
    // issue next part's loads (in flight across the compute phase)
    if (p + 1 < 3) {
      const float* Xn = Xarr[p + 1];
#pragma unroll
      for (int h = 0; h < 4; ++h) {
        int f = tid + h * 256, row = f >> 4, fc = f & 15, grow = r0 + row;
        if (grow < n) {
          const float4* s = (const float4*)(Xn + (size_t)grow * NF + fc * 8);
          pa0[h] = s[0]; pa1[h] = s[1];
        }
      }
    }
    __syncthreads();
#pragma unroll
    for (int ks = 0; ks < 4; ++ks)
      gemm_step<8, 4>(AHI, ALO, Wp, p * 4 + ks, lane, wm, wn, acc);
    __syncthreads();
  }
  // epilogue: C/D layout col=lane&15, row=(lane>>4)*4+i
#pragma unroll
  for (int mt = 0; mt < 2; ++mt) {
#pragma unroll
    for (int i = 0; i < 4; ++i) {
      int row = r0 + wm * 32 + mt * 16 + (lane >> 4) * 4 + i;
      if (row < n) {
#pragma unroll
        for (int j = 0; j < 4; ++j) {
          int col = wn * 64 + j * 16 + (lane & 15);
          float v = acc[mt][j][i] + bias[col];
          out[(size_t)row * NF + col] = fmaxf(v, 0.f);
        }
      }
    }
  }
}

// ---------------- fused tail: Y = relu([X,T1,T2]@W3^T+b3)+X ; H = relu(Y@Wm1^T+bm1);
//                  out = H@Wm2^T+bm2.  Y and H never leave the chip. ----------------
__global__ __launch_bounds__(256) void fused_tail_kernel(
    const float* __restrict__ X, const float* __restrict__ T1, const float* __restrict__ T2,
    const ushort8* __restrict__ Wp3, const float* __restrict__ b3,
    const ushort8* __restrict__ WpM1, const float* __restrict__ bm1,
    const ushort8* __restrict__ WpM2, const float* __restrict__ bm2,
    float* __restrict__ out, int n) {
  __shared__ float4 AHI[1024];
  __shared__ float4 ALO[1024];
  unsigned short* AHu = (unsigned short*)AHI;
  unsigned short* ALu = (unsigned short*)ALO;

  int tid = threadIdx.x;
  int lane = tid & 63, wid = tid >> 6;
  int wm = wid >> 1, wn = wid & 1;
  int r0 = blockIdx.x * 64;

  f32x4 acc[2][4];
#pragma unroll
  for (int mt = 0; mt < 2; ++mt)
#pragma unroll
    for (int j = 0; j < 4; ++j) acc[mt][j] = (f32x4)0.f;

  // ---- phase 1: conv2 GEMM over parts {X, T1, T2}
  const float* Xarr[3] = {X, T1, T2};
  float4 pa0[4], pa1[4];
#pragma unroll
  for (int h = 0; h < 4; ++h) {
    int f = tid + h * 256, row = f >> 4, fc = f & 15, grow = r0 + row;
    float4 z = make_float4(0.f, 0.f, 0.f, 0.f);
    pa0[h] = z; pa1[h] = z;
    if (grow < n) {
      const float4* s = (const float4*)(X + (size_t)grow * NF + fc * 8);
      pa0[h] = s[0]; pa1[h] = s[1];
    }
  }
#pragma unroll
  for (int p = 0; p < 3; ++p) {
#pragma unroll
    for (int h = 0; h < 4; ++h) {
      int f = tid + h * 256, row = f >> 4, fc = f & 15;
      cvt_frag(pa0[h], pa1[h], AHI, ALO, row * 16 + (fc ^ (row & 15)));
    }
    if (p + 1 < 3) {
      const float* Xn = Xarr[p + 1];
#pragma unroll
      for (int h = 0; h < 4; ++h) {
        int f = tid + h * 256, row = f >> 4, fc = f & 15, grow = r0 + row;
        if (grow < n) {
          const float4* s = (const float4*)(Xn + (size_t)grow * NF + fc * 8);
          pa0[h] = s[0]; pa1[h] = s[1];
        }
      }
    }
    __syncthreads();
#pragma unroll
    for (int ks = 0; ks < 4; ++ks)
      gemm_step<8, 4>(AHI, ALO, Wp3, p * 4 + ks, lane, wm, wn, acc);
    __syncthreads();
  }
  // ---- epilogue 1: Y = relu(acc+b3)+X, scatter-convert into LDS A-layout
#pragma unroll
  for (int mt = 0; mt < 2; ++mt) {
#pragma unroll
    for (int i = 0; i < 4; ++i) {
      int lrow = wm * 32 + mt * 16 + (lane >> 4) * 4 + i;
      int row = r0 + lrow;
      bool ok = row < n;
#pragma unroll
      for (int j = 0; j < 4; ++j) {
        int col = wn * 64 + j * 16 + (lane & 15);
        float v = 0.f;
        if (ok) {
          v = fmaxf(acc[mt][j][i] + b3[col], 0.f) + X[(size_t)row * NF + col];
        }
        lds_put_split(AHu, ALu, lrow, col, v);
      }
    }
  }
  __syncthreads();
  // ---- phase 2: H = relu(Y @ Wm1^T + bm1)
  f32x4 acc2[2][4];
#pragma unroll
  for (int mt = 0; mt < 2; ++mt)
#pragma unroll
    for (int j = 0; j < 4; ++j) acc2[mt][j] = (f32x4)0.f;
#pragma unroll
  for (int ks = 0; ks < 4; ++ks)
    gemm_step<8, 4>(AHI, ALO, WpM1, ks, lane, wm, wn, acc2);
  __syncthreads();   // all reads of Y done before overwrite
  // ---- epilogue 2: scatter H into LDS A-layout
#pragma unroll
  for (int mt = 0; mt < 2; ++mt) {
#pragma unroll
    for (int i = 0; i < 4; ++i) {
      int lrow = wm * 32 + mt * 16 + (lane >> 4) * 4 + i;
      int row = r0 + lrow;
      bool ok = row < n;
#pragma unroll
      for (int j = 0; j < 4; ++j) {
        int col = wn * 64 + j * 16 + (lane & 15);
        float v = ok ? fmaxf(acc2[mt][j][i] + bm1[col], 0.f) : 0.f;
        lds_put_split(AHu, ALu, lrow, col, v);
      }
    }
  }
  __syncthreads();
  // ---- phase 3: out = H @ Wm2^T + bm2   (NC=64 -> NT=4, NT2=2)
  f32x4 acc3[2][2];
#pragma unroll
  for (int mt = 0; mt < 2; ++mt)
#pragma unroll
    for (int j = 0; j < 2; ++j) acc3[mt][j] = (f32x4)0.f;
#pragma unroll
  for (int ks = 0; ks < 4; ++ks)
    gemm_step<4, 2>(AHI, ALO, WpM2, ks, lane, wm, wn, acc3);
  // ---- epilogue 3: write final output (N x 64)
#pragma unroll
  for (int mt = 0; mt < 2; ++mt) {
#pragma unroll
    for (int i = 0; i < 4; ++i) {
      int row = r0 + wm * 32 + mt * 16 + (lane >> 4) * 4 + i;
      if (row < n) {
#pragma unroll
        for (int j = 0; j < 2; ++j) {
          int col = wn * 32 + j * 16 + (lane & 15);
          out[(size_t)row * 64 + col] = acc3[mt][j][i] + bm2[col];
        }
      }
    }
  }
}

// ---------------- BatchNorm ----------------
__global__ void bn_stats_kernel(const float* __restrict__ x, float* __restrict__ stats, int n) {
  int c = threadIdx.x;   // 128
  float s = 0.f, s2 = 0.f;
  for (int r = blockIdx.x; r < n; r += gridDim.x) {
    float v = x[(size_t)r * NF + c];
    s += v;
    s2 += v * v;
  }
  atomicAdd(&stats[c], s);
  atomicAdd(&stats[NF + c], s2);
}

__global__ void bn_scale_kernel(const float* __restrict__ stats, const float* __restrict__ gamma,
                                const float* __restrict__ beta, float* __restrict__ sc,
                                float* __restrict__ sh, float n) {
  int c = threadIdx.x;   // 128
  float mu = stats[c] / n;
  float var = stats[NF + c] / n - mu * mu;
  float s = gamma[c] * rsqrtf(var + 1e-5f);
  sc[c] = s;
  sh[c] = beta[c] - mu * s;
}

__global__ void bn_apply_kernel(float* __restrict__ x, const float* __restrict__ sc,
                                const float* __restrict__ sh, const float* __restrict__ dinv,
                                _Float16* __restrict__ xs16, int n) {
  int i = blockIdx.x * 256 + threadIdx.x;   // float4 index
  if (i < n * (NF / 4)) {
    int row = i >> 5;
    int c0 = (i & 31) * 4;
    float4 v = ((const float4*)x)[i];
    v.x = v.x * sc[c0 + 0] + sh[c0 + 0];
    v.y = v.y * sc[c0 + 1] + sh[c0 + 1];
    v.z = v.z * sc[c0 + 2] + sh[c0 + 2];
    v.w = v.w * sc[c0 + 3] + sh[c0 + 3];
    ((float4*)x)[i] = v;
    float d = dinv[row];
    half4 h;
    h[0] = (_Float16)(v.x * d); h[1] = (_Float16)(v.y * d);
    h[2] = (_Float16)(v.z * d); h[3] = (_Float16)(v.w * d);
    ((half4*)xs16)[i] = h;
  }
}

// ---------------- launcher ----------------
extern "C" void kernel_launch(void* const* d_in, const int* in_sizes, int n_in,
                              void* d_out, int out_size, void* d_ws, size_t ws_size,
                              hipStream_t stream) {
  const float* feat  = (const float*)d_in[0];
  const int*   src   = (const int*)d_in[1];
  const int*   dst   = (const int*)d_in[2];
  const float* W1    = (const float*)d_in[3];
  const float* b1    = (const float*)d_in[4];
  const float* W3    = (const float*)d_in[5];
  const float* b3    = (const float*)d_in[6];
  const float* gamma = (const float*)d_in[7];
  const float* beta  = (const float*)d_in[8];
  const float* Wm1   = (const float*)d_in[9];
  const float* bm1   = (const float*)d_in[10];
  const float* Wm2   = (const float*)d_in[11];
  const float* bm2   = (const float*)d_in[12];
  int n = in_sizes[0] / NF;
  int e = in_sizes[1];

  char* p = (char*)d_ws;
  auto alloc = [&](size_t bytes) {
    char* r = p;
    p += (bytes + 255) & ~size_t(255);
    return r;
  };
  int nblk  = ceil_div(e, 4096);   // multisplit tiles
  int nbuck = ceil_div(n, 256);    // node buckets

  float* dinv     = (float*)alloc((size_t)n * 4);
  int*   offsets  = (int*)alloc((size_t)(n + 1) * 4);
  int*   counts   = (int*)alloc((size_t)nblk * nbuck * 4);
  int*   btot     = (int*)alloc((size_t)nbuck * 4);
  int*   bbase    = (int*)alloc((size_t)(nbuck + 1) * 4);
  int*   csr      = (int*)alloc((size_t)e * 4);
  float* stats    = (float*)alloc(256 * 4);
  float* bnsc     = (float*)alloc(128 * 4);
  float* bnsh     = (float*)alloc(128 * 4);
  ushort8* Wp1  = (ushort8*)alloc(12 * 8 * 2 * 64 * 16);   // K=384, NT=8
  ushort8* Wp3  = (ushort8*)alloc(12 * 8 * 2 * 64 * 16);
  ushort8* WpM1 = (ushort8*)alloc(4 * 8 * 2 * 64 * 16);    // K=128, NT=8
  ushort8* WpM2 = (ushort8*)alloc(4 * 4 * 2 * 64 * 16);    // K=128, NT=4
  size_t matb = (size_t)n * NF * 4;
  float* T1 = (float*)alloc(matb);
  float* T2 = (float*)alloc(matb);
  float* X  = (float*)alloc(matb);   // conv1 out -> BN in place -> x_res
  _Float16* xsA  = (_Float16*)alloc((size_t)n * NF * 2);  // Fs16 then Xs16
  _Float16* xsB  = (_Float16*)alloc((size_t)n * NF * 2);  // T1s16 (both convs)
  int2* binned = (int2*)T2;          // alias: 6.4MB scratch, dead before spmv writes T2

  hipMemsetAsync(stats, 0, 256 * 4, stream);

  int fb = ceil_div(n * (NF / 4), 256);      // float4-grid over matrices
  int sb = ceil_div(n, 4);                   // spmv: 4 nodes/block
  int gb = ceil_div(n, 64);                  // gemm: 64 rows/block

  // CSR build (sorted by dst) via two-level multisplit; also emits offsets/dinv
  bucket_hist_kernel<<<nblk, 256, 0, stream>>>(dst, counts, e, nblk, nbuck);
  bucket_scan_rows_kernel<<<nbuck, 256, 0, stream>>>(counts, btot, nblk);
  bucket_base_kernel<<<1, 256, 0, stream>>>(btot, bbase, nbuck, e);
  bucket_bin_kernel<<<nblk, 256, 0, stream>>>(src, dst, counts, bbase, binned, e, nblk, nbuck);
  bucket_finalize_kernel<<<nbuck, 256, 0, stream>>>(binned, bbase, offsets, csr, dinv, n, e, nbuck);

  // W split+pack (one launch)
  pack_all_kernel<<<120, 256, 0, stream>>>(W1, Wp1, W3, Wp3, Wm1, WpM1, Wm2, WpM2);

  // conv1: T1 = -A^ F ; T2 = -2 A^ T1 - F ; X = relu([F,T1,T2] @ W1^T + b1)
  scale16_kernel<<<fb, 256, 0, stream>>>(feat, dinv, xsA, n);
  spmv_kernel<<<sb, 256, 0, stream>>>(xsA, dinv, offsets, csr, nullptr, -1.f, 0.f, T1, xsB, n);
  spmv_kernel<<<sb, 256, 0, stream>>>(xsB, dinv, offsets, csr, feat, -2.f, -1.f, T2, nullptr, n);
  mfma_gemm3_kernel<<<gb, 256, 0, stream>>>(feat, T1, T2, Wp1, b1, X, n);

  // BatchNorm (training stats, biased var), in place; X becomes x_res; xsA = fp16(X*dinv)
  bn_stats_kernel<<<512, 128, 0, stream>>>(X, stats, n);
  bn_scale_kernel<<<1, 128, 0, stream>>>(stats, gamma, beta, bnsc, bnsh, (float)n);
  bn_apply_kernel<<<fb, 256, 0, stream>>>(X, bnsc, bnsh, dinv, xsA, n);

  // conv2 spmvs
  spmv_kernel<<<sb, 256, 0, stream>>>(xsA, dinv, offsets, csr, nullptr, -1.f, 0.f, T1, xsB, n);
  spmv_kernel<<<sb, 256, 0, stream>>>(xsB, dinv, offsets, csr, X, -2.f, -1.f, T2, nullptr, n);

  // fused conv2-GEMM + residual + MLP1 + MLP2 (Y, H stay on-chip)
  fused_tail_kernel<<<gb, 256, 0, stream>>>(X, T1, T2, Wp3, b3, WpM1, bm1, WpM2, bm2,
                                            (float*)d_out, n);
}

// Round 8
// 351.802 us; speedup vs baseline: 1.0049x; 1.0049x over previous
//
#include <hip/hip_runtime.h>
#include <hip/hip_bf16.h>
#include <math.h>

#define NF 128   // IN_F == HID == 128

typedef __bf16 bf16x8 __attribute__((ext_vector_type(8)));
typedef unsigned short ushort8 __attribute__((ext_vector_type(8)));
typedef float f32x4 __attribute__((ext_vector_type(4)));
typedef _Float16 half8 __attribute__((ext_vector_type(8)));
typedef _Float16 half4 __attribute__((ext_vector_type(4)));

static inline int ceil_div(int a, int b) { return (a + b - 1) / b; }

// ================= CSR build: two-level multisplit counting sort =================
// bucket = dst >> 8 (256 nodes per bucket). TILE = 4096 edges per block.

__global__ __launch_bounds__(256) void bucket_hist_kernel(const int* __restrict__ dst,
                                                          int* __restrict__ counts,
                                                          int e, int nblk, int nbuck) {
  __shared__ int h[256];
  int t = threadIdx.x, blk = blockIdx.x;
  h[t] = 0;
  __syncthreads();
  int base = blk * 4096;
#pragma unroll
  for (int k = 0; k < 16; ++k) {
    int i = base + k * 256 + t;
    if (i < e) atomicAdd(&h[dst[i] >> 8], 1);
  }
  __syncthreads();
  for (int b = t; b < nbuck; b += 256) counts[b * nblk + blk] = h[b];
}

__global__ __launch_bounds__(256) void bucket_scan_rows_kernel(int* __restrict__ counts,
                                                               int* __restrict__ btot,
                                                               int nblk) {
  __shared__ int sh[256];
  int b = blockIdx.x, t = threadIdx.x;
  int* row = counts + (size_t)b * nblk;
  int carry = 0;
  for (int base = 0; base < nblk; base += 256) {
    int v = (base + t < nblk) ? row[base + t] : 0;
    sh[t] = v;
    __syncthreads();
    for (int off = 1; off < 256; off <<= 1) {
      int add = (t >= off) ? sh[t - off] : 0;
      __syncthreads();
      sh[t] += add;
      __syncthreads();
    }
    if (base + t < nblk) row[base + t] = carry + sh[t] - v;
    carry += sh[255];
    __syncthreads();
  }
  if (t == 0) btot[b] = carry;
}

__global__ __launch_bounds__(256) void bucket_base_kernel(const int* __restrict__ btot,
                                                          int* __restrict__ bbase,
                                                          int nbuck, int e) {
  __shared__ int sh[256];
  __shared__ int carry;
  int t = threadIdx.x;
  if (t == 0) carry = 0;
  __syncthreads();
  for (int base = 0; base < nbuck; base += 256) {
    int v = (base + t < nbuck) ? btot[base + t] : 0;
    sh[t] = v;
    __syncthreads();
    for (int off = 1; off < 256; off <<= 1) {
      int add = (t >= off) ? sh[t - off] : 0;
      __syncthreads();
      sh[t] += add;
      __syncthreads();
    }
    if (base + t < nbuck) bbase[base + t] = carry + sh[t] - v;
    __syncthreads();
    if (t == 0) carry += sh[255];
    __syncthreads();
  }
  if (t == 0) bbase[nbuck] = e;
}

__global__ __launch_bounds__(256) void bucket_bin_kernel(const int* __restrict__ src,
                                                         const int* __restrict__ dst,
                                                         const int* __restrict__ counts,
                                                         const int* __restrict__ bbase,
                                                         int2* __restrict__ binned,
                                                         int e, int nblk, int nbuck) {
  __shared__ int cur[256];
  int t = threadIdx.x, blk = blockIdx.x;
  for (int b = t; b < nbuck; b += 256) cur[b] = counts[b * nblk + blk] + bbase[b];
  __syncthreads();
  int base = blk * 4096;
#pragma unroll
  for (int k = 0; k < 16; ++k) {
    int i = base + k * 256 + t;
    if (i < e) {
      int d = dst[i];
      int pos = atomicAdd(&cur[d >> 8], 1);
      binned[pos] = make_int2(src[i], d);
    }
  }
}

__global__ __launch_bounds__(256) void bucket_finalize_kernel(const int2* __restrict__ binned,
                                                              const int* __restrict__ bbase,
                                                              int* __restrict__ offsets,
                                                              int* __restrict__ csr,
                                                              float* __restrict__ dinv,
                                                              int n, int e, int nbuck) {
  __shared__ int deg[256];
  __shared__ int offs[256];
  __shared__ int cur[256];
  int b = blockIdx.x, t = threadIdx.x;
  int ebeg = bbase[b];
  int eend = bbase[b + 1];
  deg[t] = 0;
  __syncthreads();
  for (int j = ebeg + t; j < eend; j += 256) atomicAdd(&deg[binned[j].y & 255], 1);
  __syncthreads();
  int v = deg[t];
  offs[t] = v;
  __syncthreads();
  for (int off = 1; off < 256; off <<= 1) {
    int add = (t >= off) ? offs[t - off] : 0;
    __syncthreads();
    offs[t] += add;
    __syncthreads();
  }
  int excl = offs[t] - v;
  cur[t] = excl;
  int node = b * 256 + t;
  if (node < n) {
    offsets[node] = ebeg + excl;
    float d = (float)(v > 1 ? v : 1);
    dinv[node] = rsqrtf(d);
  }
  if (b == nbuck - 1 && t == 0) offsets[n] = e;
  __syncthreads();
  for (int j = ebeg + t; j < eend; j += 256) {
    int2 pr = binned[j];
    int pos = atomicAdd(&cur[pr.y & 255], 1);
    csr[ebeg + pos] = pr.x;
  }
}

// ---------------- scale16: out16[r][c] = fp16(x[r][c] * dinv[r]) ----------------
__global__ void scale16_kernel(const float* __restrict__ x, const float* __restrict__ dinv,
                               _Float16* __restrict__ out16, int n) {
  int i = blockIdx.x * 256 + threadIdx.x;   // float4 index, 32 per row
  if (i < n * (NF / 4)) {
    int row = i >> 5;
    float4 v = ((const float4*)x)[i];
    float d = dinv[row];
    half4 h;
    h[0] = (_Float16)(v.x * d); h[1] = (_Float16)(v.y * d);
    h[2] = (_Float16)(v.z * d); h[3] = (_Float16)(v.w * d);
    ((half4*)out16)[i] = h;
  }
}

// ---------------- SpMV (fp16 pre-scaled gather source) ----------------
__global__ __launch_bounds__(256) void spmv_kernel(
    const _Float16* __restrict__ xs16, const float* __restrict__ dinv,
    const int* __restrict__ offsets, const int* __restrict__ csr,
    const float* __restrict__ z, float a, float bz,
    float* __restrict__ out, _Float16* __restrict__ outs16, int n) {
  int w = threadIdx.x >> 6, lane = threadIdx.x & 63;
  int node = blockIdx.x * 4 + w;
  if (node >= n) return;
  int beg = __builtin_amdgcn_readfirstlane(offsets[node]);
  int end = __builtin_amdgcn_readfirstlane(offsets[node + 1]);
  int eh = lane >> 4;        // which edge of the quad (0..3)
  int cq = lane & 15;        // half8 slot within the 128-half row

  float acc[8];
#pragma unroll
  for (int j = 0; j < 8; ++j) acc[j] = 0.f;

  int e2 = beg;
  for (; e2 + 8 <= end; e2 += 8) {
    int s0 = csr[e2 + eh];
    int s1 = csr[e2 + 4 + eh];
    half8 g0 = ((const half8*)(xs16 + (size_t)s0 * NF))[cq];
    half8 g1 = ((const half8*)(xs16 + (size_t)s1 * NF))[cq];
#pragma unroll
    for (int j = 0; j < 8; ++j) acc[j] += (float)g0[j];
#pragma unroll
    for (int j = 0; j < 8; ++j) acc[j] += (float)g1[j];
  }
  for (; e2 + 4 <= end; e2 += 4) {
    int s0 = csr[e2 + eh];
    half8 g0 = ((const half8*)(xs16 + (size_t)s0 * NF))[cq];
#pragma unroll
    for (int j = 0; j < 8; ++j) acc[j] += (float)g0[j];
  }
  int rem = end - e2;
  if (eh < rem) {
    int s0 = csr[e2 + eh];
    half8 g0 = ((const half8*)(xs16 + (size_t)s0 * NF))[cq];
#pragma unroll
    for (int j = 0; j < 8; ++j) acc[j] += (float)g0[j];
  }
#pragma unroll
  for (int j = 0; j < 8; ++j) {
    acc[j] += __shfl_xor(acc[j], 16);
    acc[j] += __shfl_xor(acc[j], 32);
  }
  if (eh == 0) {
    float dv = dinv[node];
    float v[8];
#pragma unroll
    for (int j = 0; j < 8; ++j) v[j] = a * dv * acc[j];
    if (z) {
      const f32x4* zp = (const f32x4*)(z + (size_t)node * NF + cq * 8);
      f32x4 z0 = zp[0], z1 = zp[1];
#pragma unroll
      for (int j = 0; j < 4; ++j) { v[j] += bz * z0[j]; v[4 + j] += bz * z1[j]; }
    }
    f32x4 o0, o1;
#pragma unroll
    for (int j = 0; j < 4; ++j) { o0[j] = v[j]; o1[j] = v[4 + j]; }
    f32x4* op = (f32x4*)(out + (size_t)node * NF + cq * 8);
    op[0] = o0; op[1] = o1;
    if (outs16) {
      half8 hv;
#pragma unroll
      for (int j = 0; j < 8; ++j) hv[j] = (_Float16)(v[j] * dv);
      *(half8*)(outs16 + (size_t)node * NF + cq * 8) = hv;
    }
  }
}

// ---------------- W pre-split + frag-pack ----------------
__device__ __forceinline__ void pack_one(const float* __restrict__ W, ushort8* __restrict__ Wp,
                                         int f, int NT, int K) {
  int lane = f & 63;
  int hl = (f >> 6) & 1;
  int rest = f >> 7;
  int nt = rest % NT;
  int kunit = rest / NT;
  int nrow = nt * 16 + (lane & 15);
  int k0 = kunit * 32 + (lane >> 4) * 8;
  const float* srcp = W + (size_t)nrow * K + k0;
  ushort8 v;
#pragma unroll
  for (int j = 0; j < 8; ++j) {
    float x = srcp[j];
    __bf16 h = (__bf16)x;
    if (hl) h = (__bf16)(x - (float)h);
    v[j] = __builtin_bit_cast(unsigned short, h);
  }
  Wp[f] = v;
}

__global__ void pack_all_kernel(const float* __restrict__ W1, ushort8* __restrict__ P1,
                                const float* __restrict__ W3, ushort8* __restrict__ P3,
                                const float* __restrict__ Wm1, ushort8* __restrict__ PM1,
                                const float* __restrict__ Wm2, ushort8* __restrict__ PM2) {
  int f = blockIdx.x * 256 + threadIdx.x;
  if (f < 12288) pack_one(W1, P1, f, 8, 384);
  else if (f < 24576) pack_one(W3, P3, f - 12288, 8, 384);
  else if (f < 28672) pack_one(Wm1, PM1, f - 24576, 8, 128);
  else if (f < 30720) pack_one(Wm2, PM2, f - 28672, 4, 128);
}

// ================= split-bf16 MFMA GEMM machinery (32-row blocks) =================
// LDS A-layout: AHI/ALO [32 rows][16 frags] bf16x8, frag slot XOR-swizzled by row&15.
// Block = 256 thr = 4 waves (wm in {0,1} x wn in {0,1}); wave tile 16 rows x 64 cols.

__device__ __forceinline__ void lds_put_split(unsigned short* AH, unsigned short* AL,
                                              int row, int col, float v) {
  __bf16 hh = (__bf16)v;
  __bf16 ll = (__bf16)(v - (float)hh);
  int off = row * 128 + ((((col >> 3) ^ (row & 15))) << 3) + (col & 7);
  AH[off] = __builtin_bit_cast(unsigned short, hh);
  AL[off] = __builtin_bit_cast(unsigned short, ll);
}

__device__ __forceinline__ void cvt_frag(const float4& a, const float4& b,
                                         float4* AHI, float4* ALO, int idx) {
  float xv[8] = {a.x, a.y, a.z, a.w, b.x, b.y, b.z, b.w};
  ushort8 hi, lo;
#pragma unroll
  for (int j = 0; j < 8; ++j) {
    __bf16 hh = (__bf16)xv[j];
    __bf16 ll = (__bf16)(xv[j] - (float)hh);
    hi[j] = __builtin_bit_cast(unsigned short, hh);
    lo[j] = __builtin_bit_cast(unsigned short, ll);
  }
  AHI[idx] = __builtin_bit_cast(float4, hi);
  ALO[idx] = __builtin_bit_cast(float4, lo);
}

// one 16-row-per-wave x NT2*16-col x 32k MFMA pass (3 split-bf16 MFMAs per tile)
template<int NT, int NT2>
__device__ __forceinline__ void gemm_step32(const float4* AHI, const float4* ALO,
                                            const ushort8* __restrict__ Wp, int kunit,
                                            int lane, int wm, int wn, f32x4* acc) {
  int arow = wm * 16 + (lane & 15);
  int fc = (kunit & 3) * 4 + (lane >> 4);
  int idx = arow * 16 + (fc ^ (arow & 15));
  bf16x8 ah = __builtin_bit_cast(bf16x8, AHI[idx]);
  bf16x8 al = __builtin_bit_cast(bf16x8, ALO[idx]);
#pragma unroll
  for (int j = 0; j < NT2; ++j) {
    int nt = wn * NT2 + j;
    const ushort8* bp = Wp + (size_t)(kunit * NT + nt) * 2 * 64 + lane;
    bf16x8 bh = __builtin_bit_cast(bf16x8, bp[0]);
    bf16x8 bl = __builtin_bit_cast(bf16x8, bp[64]);
    acc[j] = __builtin_amdgcn_mfma_f32_16x16x32_bf16(ah, bh, acc[j], 0, 0, 0);
    acc[j] = __builtin_amdgcn_mfma_f32_16x16x32_bf16(ah, bl, acc[j], 0, 0, 0);
    acc[j] = __builtin_amdgcn_mfma_f32_16x16x32_bf16(al, bh, acc[j], 0, 0, 0);
  }
}

// ---------------- conv1 GEMM + fused BN partial stats ----------------
__global__ __launch_bounds__(256, 6) void conv1_gemm_kernel(
    const float* __restrict__ X0, const float* __restrict__ X1, const float* __restrict__ X2,
    const ushort8* __restrict__ Wp, const float* __restrict__ bias,
    float* __restrict__ out, float* __restrict__ stats, int n) {
  __shared__ float4 AHI[512];   // 32 rows x 16 frags
  __shared__ float4 ALO[512];
  __shared__ float sstat[256];

  int tid = threadIdx.x;
  int lane = tid & 63, wid = tid >> 6;
  int wm = wid >> 1, wn = wid & 1;
  int r0 = blockIdx.x * 32;

  f32x4 acc[4];
#pragma unroll
  for (int j = 0; j < 4; ++j) acc[j] = (f32x4)0.f;

  const float* Xarr[3] = {X0, X1, X2};
  float4 pa0[2], pa1[2];
#pragma unroll
  for (int h = 0; h < 2; ++h) {
    int f = tid + h * 256, row = f >> 4, fc = f & 15, grow = r0 + row;
    float4 z = make_float4(0.f, 0.f, 0.f, 0.f);
    pa0[h] = z; pa1[h] = z;
    if (grow < n) {
      const float4* s = (const float4*)(X0 + (size_t)grow * NF + fc * 8);
      pa0[h] = s[0]; pa1[h] = s[1];
    }
  }
#pragma unroll
  for (int p = 0; p < 3; ++p) {
#pragma unroll
    for (int h = 0; h < 2; ++h) {
      int f = tid + h * 256, row = f >> 4, fc = f & 15;
      cvt_frag(pa0[h], pa1[h], AHI, ALO, row * 16 + (fc ^ (row & 15)));
    }
    if (p + 1 < 3) {
      const float* Xn = Xarr[p + 1];
#pragma unroll
      for (int h = 0; h < 2; ++h) {
        int f = tid + h * 256, row = f >> 4, fc = f & 15, grow = r0 + row;
        if (grow < n) {
          const float4* s = (const float4*)(Xn + (size_t)grow * NF + fc * 8);
          pa0[h] = s[0]; pa1[h] = s[1];
        }
      }
    }
    __syncthreads();
#pragma unroll
    for (int ks = 0; ks < 4; ++ks)
      gemm_step32<8, 4>(AHI, ALO, Wp, p * 4 + ks, lane, wm, wn, acc);
    __syncthreads();
  }
  // epilogue: relu + store + BN partial stats (shfl reduce -> LDS -> global atomics)
  sstat[tid] = 0.f;
  __syncthreads();
  int rbase = r0 + wm * 16 + (lane >> 4) * 4;
#pragma unroll
  for (int j = 0; j < 4; ++j) {
    int col = wn * 64 + j * 16 + (lane & 15);
    float b = bias[col];
    float sj = 0.f, qj = 0.f;
#pragma unroll
    for (int i = 0; i < 4; ++i) {
      int row = rbase + i;
      if (row < n) {
        float v = fmaxf(acc[j][i] + b, 0.f);
        out[(size_t)row * NF + col] = v;
        sj += v; qj += v * v;
      }
    }
    sj += __shfl_xor(sj, 16); sj += __shfl_xor(sj, 32);
    qj += __shfl_xor(qj, 16); qj += __shfl_xor(qj, 32);
    if ((lane >> 4) == 0) {
      atomicAdd(&sstat[col], sj);
      atomicAdd(&sstat[128 + col], qj);
    }
  }
  __syncthreads();
  atomicAdd(&stats[tid], sstat[tid]);
}

// ---------------- fused tail: Y = relu([X,T1,T2]@W3^T+b3)+X ; H = relu(Y@Wm1^T+bm1);
//                  out = H@Wm2^T+bm2.  Y and H never leave the chip. ----------------
__global__ __launch_bounds__(256, 6) void fused_tail_kernel(
    const float* __restrict__ X, const float* __restrict__ T1, const float* __restrict__ T2,
    const ushort8* __restrict__ Wp3, const float* __restrict__ b3,
    const ushort8* __restrict__ WpM1, const float* __restrict__ bm1,
    const ushort8* __restrict__ WpM2, const float* __restrict__ bm2,
    float* __restrict__ out, int n) {
  __shared__ float4 AHI[512];
  __shared__ float4 ALO[512];
  unsigned short* AHu = (unsigned short*)AHI;
  unsigned short* ALu = (unsigned short*)ALO;

  int tid = threadIdx.x;
  int lane = tid & 63, wid = tid >> 6;
  int wm = wid >> 1, wn = wid & 1;
  int r0 = blockIdx.x * 32;

  f32x4 acc[4];
#pragma unroll
  for (int j = 0; j < 4; ++j) acc[j] = (f32x4)0.f;

  // ---- phase 1: conv2 GEMM over parts {X, T1, T2}
  const float* Xarr[3] = {X, T1, T2};
  float4 pa0[2], pa1[2];
#pragma unroll
  for (int h = 0; h < 2; ++h) {
    int f = tid + h * 256, row = f >> 4, fc = f & 15, grow = r0 + row;
    float4 z = make_float4(0.f, 0.f, 0.f, 0.f);
    pa0[h] = z; pa1[h] = z;
    if (grow < n) {
      const float4* s = (const float4*)(X + (size_t)grow * NF + fc * 8);
      pa0[h] = s[0]; pa1[h] = s[1];
    }
  }
#pragma unroll
  for (int p = 0; p < 3; ++p) {
#pragma unroll
    for (int h = 0; h < 2; ++h) {
      int f = tid + h * 256, row = f >> 4, fc = f & 15;
      cvt_frag(pa0[h], pa1[h], AHI, ALO, row * 16 + (fc ^ (row & 15)));
    }
    if (p + 1 < 3) {
      const float* Xn = Xarr[p + 1];
#pragma unroll
      for (int h = 0; h < 2; ++h) {
        int f = tid + h * 256, row = f >> 4, fc = f & 15, grow = r0 + row;
        if (grow < n) {
          const float4* s = (const float4*)(Xn + (size_t)grow * NF + fc * 8);
          pa0[h] = s[0]; pa1[h] = s[1];
        }
      }
    }
    __syncthreads();
#pragma unroll
    for (int ks = 0; ks < 4; ++ks)
      gemm_step32<8, 4>(AHI, ALO, Wp3, p * 4 + ks, lane, wm, wn, acc);
    __syncthreads();
  }
  // ---- epilogue 1: Y = relu(acc+b3)+X, scatter-convert into LDS A-layout
  int rb = wm * 16 + (lane >> 4) * 4;
#pragma unroll
  for (int j = 0; j < 4; ++j) {
    int col = wn * 64 + j * 16 + (lane & 15);
    float b = b3[col];
#pragma unroll
    for (int i = 0; i < 4; ++i) {
      int lrow = rb + i;
      int row = r0 + lrow;
      float v = 0.f;
      if (row < n) v = fmaxf(acc[j][i] + b, 0.f) + X[(size_t)row * NF + col];
      lds_put_split(AHu, ALu, lrow, col, v);
    }
  }
  __syncthreads();
  // ---- phase 2: H = relu(Y @ Wm1^T + bm1)
  f32x4 acc2[4];
#pragma unroll
  for (int j = 0; j < 4; ++j) acc2[j] = (f32x4)0.f;
#pragma unroll
  for (int ks = 0; ks < 4; ++ks)
    gemm_step32<8, 4>(AHI, ALO, WpM1, ks, lane, wm, wn, acc2);
  __syncthreads();   // all reads of Y done before overwrite
  // ---- epilogue 2: scatter H into LDS A-layout
#pragma unroll
  for (int j = 0; j < 4; ++j) {
    int col = wn * 64 + j * 16 + (lane & 15);
    float b = bm1[col];
#pragma unroll
    for (int i = 0; i < 4; ++i) {
      int lrow = rb + i;
      float v = fmaxf(acc2[j][i] + b, 0.f);
      lds_put_split(AHu, ALu, lrow, col, v);
    }
  }
  __syncthreads();
  // ---- phase 3: out = H @ Wm2^T + bm2   (NC=64 -> NT=4, NT2=2)
  f32x4 acc3[2];
#pragma unroll
  for (int j = 0; j < 2; ++j) acc3[j] = (f32x4)0.f;
#pragma unroll
  for (int ks = 0; ks < 4; ++ks)
    gemm_step32<4, 2>(AHI, ALO, WpM2, ks, lane, wm, wn, acc3);
  // ---- epilogue 3: write final output (N x 64)
#pragma unroll
  for (int j = 0; j < 2; ++j) {
    int col = wn * 32 + j * 16 + (lane & 15);
    float b = bm2[col];
#pragma unroll
    for (int i = 0; i < 4; ++i) {
      int row = r0 + rb + i;
      if (row < n) out[(size_t)row * 64 + col] = acc3[j][i] + b;
    }
  }
}

// ---------------- BatchNorm scale/apply ----------------
__global__ void bn_scale_kernel(const float* __restrict__ stats, const float* __restrict__ gamma,
                                const float* __restrict__ beta, float* __restrict__ sc,
                                float* __restrict__ sh, float n) {
  int c = threadIdx.x;   // 128
  float mu = stats[c] / n;
  float var = stats[NF + c] / n - mu * mu;
  float s = gamma[c] * rsqrtf(var + 1e-5f);
  sc[c] = s;
  sh[c] = beta[c] - mu * s;
}

__global__ void bn_apply_kernel(float* __restrict__ x, const float* __restrict__ sc,
                                const float* __restrict__ sh, const float* __restrict__ dinv,
                                _Float16* __restrict__ xs16, int n) {
  int i = blockIdx.x * 256 + threadIdx.x;   // float4 index
  if (i < n * (NF / 4)) {
    int row = i >> 5;
    int c0 = (i & 31) * 4;
    float4 v = ((const float4*)x)[i];
    v.x = v.x * sc[c0 + 0] + sh[c0 + 0];
    v.y = v.y * sc[c0 + 1] + sh[c0 + 1];
    v.z = v.z * sc[c0 + 2] + sh[c0 + 2];
    v.w = v.w * sc[c0 + 3] + sh[c0 + 3];
    ((float4*)x)[i] = v;
    float d = dinv[row];
    half4 h;
    h[0] = (_Float16)(v.x * d); h[1] = (_Float16)(v.y * d);
    h[2] = (_Float16)(v.z * d); h[3] = (_Float16)(v.w * d);
    ((half4*)xs16)[i] = h;
  }
}

// ---------------- launcher ----------------
extern "C" void kernel_launch(void* const* d_in, const int* in_sizes, int n_in,
                              void* d_out, int out_size, void* d_ws, size_t ws_size,
                              hipStream_t stream) {
  const float* feat  = (const float*)d_in[0];
  const int*   src   = (const int*)d_in[1];
  const int*   dst   = (const int*)d_in[2];
  const float* W1    = (const float*)d_in[3];
  const float* b1    = (const float*)d_in[4];
  const float* W3    = (const float*)d_in[5];
  const float* b3    = (const float*)d_in[6];
  const float* gamma = (const float*)d_in[7];
  const float* beta  = (const float*)d_in[8];
  const float* Wm1   = (const float*)d_in[9];
  const float* bm1   = (const float*)d_in[10];
  const float* Wm2   = (const float*)d_in[11];
  const float* bm2   = (const float*)d_in[12];
  int n = in_sizes[0] / NF;
  int e = in_sizes[1];

  char* p = (char*)d_ws;
  auto alloc = [&](size_t bytes) {
    char* r = p;
    p += (bytes + 255) & ~size_t(255);
    return r;
  };
  int nblk  = ceil_div(e, 4096);   // multisplit tiles
  int nbuck = ceil_div(n, 256);    // node buckets

  float* dinv     = (float*)alloc((size_t)n * 4);
  int*   offsets  = (int*)alloc((size_t)(n + 1) * 4);
  int*   counts   = (int*)alloc((size_t)nblk * nbuck * 4);
  int*   btot     = (int*)alloc((size_t)nbuck * 4);
  int*   bbase    = (int*)alloc((size_t)(nbuck + 1) * 4);
  int*   csr      = (int*)alloc((size_t)e * 4);
  float* stats    = (float*)alloc(256 * 4);
  float* bnsc     = (float*)alloc(128 * 4);
  float* bnsh     = (float*)alloc(128 * 4);
  ushort8* Wp1  = (ushort8*)alloc(12 * 8 * 2 * 64 * 16);   // K=384, NT=8
  ushort8* Wp3  = (ushort8*)alloc(12 * 8 * 2 * 64 * 16);
  ushort8* WpM1 = (ushort8*)alloc(4 * 8 * 2 * 64 * 16);    // K=128, NT=8
  ushort8* WpM2 = (ushort8*)alloc(4 * 4 * 2 * 64 * 16);    // K=128, NT=4
  size_t matb = (size_t)n * NF * 4;
  float* T1 = (float*)alloc(matb);
  float* T2 = (float*)alloc(matb);
  float* X  = (float*)alloc(matb);   // conv1 out -> BN in place -> x_res
  _Float16* xsA  = (_Float16*)alloc((size_t)n * NF * 2);  // Fs16 then Xs16
  _Float16* xsB  = (_Float16*)alloc((size_t)n * NF * 2);  // T1s16 (both convs)
  int2* binned = (int2*)T2;          // alias: 6.4MB scratch, dead before spmv writes T2

  hipMemsetAsync(stats, 0, 256 * 4, stream);

  int fb = ceil_div(n * (NF / 4), 256);      // float4-grid over matrices
  int sb = ceil_div(n, 4);                   // spmv: 4 nodes/block
  int gb32 = ceil_div(n, 32);                // gemm: 32 rows/block

  // CSR build (sorted by dst) via two-level multisplit; also emits offsets/dinv
  bucket_hist_kernel<<<nblk, 256, 0, stream>>>(dst, counts, e, nblk, nbuck);
  bucket_scan_rows_kernel<<<nbuck, 256, 0, stream>>>(counts, btot, nblk);
  bucket_base_kernel<<<1, 256, 0, stream>>>(btot, bbase, nbuck, e);
  bucket_bin_kernel<<<nblk, 256, 0, stream>>>(src, dst, counts, bbase, binned, e, nblk, nbuck);
  bucket_finalize_kernel<<<nbuck, 256, 0, stream>>>(binned, bbase, offsets, csr, dinv, n, e, nbuck);

  // W split+pack (one launch)
  pack_all_kernel<<<120, 256, 0, stream>>>(W1, Wp1, W3, Wp3, Wm1, WpM1, Wm2, WpM2);

  // conv1: T1 = -A^ F ; T2 = -2 A^ T1 - F ; X = relu([F,T1,T2] @ W1^T + b1)  (+BN stats)
  scale16_kernel<<<fb, 256, 0, stream>>>(feat, dinv, xsA, n);
  spmv_kernel<<<sb, 256, 0, stream>>>(xsA, dinv, offsets, csr, nullptr, -1.f, 0.f, T1, xsB, n);
  spmv_kernel<<<sb, 256, 0, stream>>>(xsB, dinv, offsets, csr, feat, -2.f, -1.f, T2, nullptr, n);
  conv1_gemm_kernel<<<gb32, 256, 0, stream>>>(feat, T1, T2, Wp1, b1, X, stats, n);

  // BatchNorm finalize + apply in place; X becomes x_res; xsA = fp16(X*dinv)
  bn_scale_kernel<<<1, 128, 0, stream>>>(stats, gamma, beta, bnsc, bnsh, (float)n);
  bn_apply_kernel<<<fb, 256, 0, stream>>>(X, bnsc, bnsh, dinv, xsA, n);

  // conv2 spmvs
  spmv_kernel<<<sb, 256, 0, stream>>>(xsA, dinv, offsets, csr, nullptr, -1.f, 0.f, T1, xsB, n);
  spmv_kernel<<<sb, 256, 0, stream>>>(xsB, dinv, offsets, csr, X, -2.f, -1.f, T2, nullptr, n);

  // fused conv2-GEMM + residual + MLP1 + MLP2 (Y, H stay on-chip)
  fused_tail_kernel<<<gb32, 256, 0, stream>>>(X, T1, T2, Wp3, b3, WpM1, bm1, WpM2, bm2,
                                              (float*)d_out, n);
}

// Round 9
// 300.850 us; speedup vs baseline: 1.1751x; 1.1694x over previous
//
#include <hip/hip_runtime.h>
#include <hip/hip_bf16.h>
#include <math.h>

#define NF 128   // IN_F == HID == 128

typedef __bf16 bf16x8 __attribute__((ext_vector_type(8)));
typedef unsigned short ushort8 __attribute__((ext_vector_type(8)));
typedef float f32x4 __attribute__((ext_vector_type(4)));
typedef _Float16 half8 __attribute__((ext_vector_type(8)));
typedef _Float16 half4 __attribute__((ext_vector_type(4)));

static inline int ceil_div(int a, int b) { return (a + b - 1) / b; }

// ================= CSR build: two-level multisplit counting sort =================
// bucket = dst >> 8 (256 nodes per bucket). TILE = 4096 edges per block.

__global__ __launch_bounds__(256) void bucket_hist_kernel(const int* __restrict__ dst,
                                                          int* __restrict__ counts,
                                                          int e, int nblk, int nbuck) {
  __shared__ int h[256];
  int t = threadIdx.x, blk = blockIdx.x;
  h[t] = 0;
  __syncthreads();
  int base = blk * 4096;
#pragma unroll
  for (int k = 0; k < 16; ++k) {
    int i = base + k * 256 + t;
    if (i < e) atomicAdd(&h[dst[i] >> 8], 1);
  }
  __syncthreads();
  for (int b = t; b < nbuck; b += 256) counts[b * nblk + blk] = h[b];
}

__global__ __launch_bounds__(256) void bucket_scan_rows_kernel(int* __restrict__ counts,
                                                               int* __restrict__ btot,
                                                               int nblk) {
  __shared__ int sh[256];
  int b = blockIdx.x, t = threadIdx.x;
  int* row = counts + (size_t)b * nblk;
  int carry = 0;
  for (int base = 0; base < nblk; base += 256) {
    int v = (base + t < nblk) ? row[base + t] : 0;
    sh[t] = v;
    __syncthreads();
    for (int off = 1; off < 256; off <<= 1) {
      int add = (t >= off) ? sh[t - off] : 0;
      __syncthreads();
      sh[t] += add;
      __syncthreads();
    }
    if (base + t < nblk) row[base + t] = carry + sh[t] - v;
    carry += sh[255];
    __syncthreads();
  }
  if (t == 0) btot[b] = carry;
}

__global__ __launch_bounds__(256) void bucket_base_kernel(const int* __restrict__ btot,
                                                          int* __restrict__ bbase,
                                                          int nbuck, int e) {
  __shared__ int sh[256];
  __shared__ int carry;
  int t = threadIdx.x;
  if (t == 0) carry = 0;
  __syncthreads();
  for (int base = 0; base < nbuck; base += 256) {
    int v = (base + t < nbuck) ? btot[base + t] : 0;
    sh[t] = v;
    __syncthreads();
    for (int off = 1; off < 256; off <<= 1) {
      int add = (t >= off) ? sh[t - off] : 0;
      __syncthreads();
      sh[t] += add;
      __syncthreads();
    }
    if (base + t < nbuck) bbase[base + t] = carry + sh[t] - v;
    __syncthreads();
    if (t == 0) carry += sh[255];
    __syncthreads();
  }
  if (t == 0) bbase[nbuck] = e;
}

__global__ __launch_bounds__(256) void bucket_bin_kernel(const int* __restrict__ src,
                                                         const int* __restrict__ dst,
                                                         const int* __restrict__ counts,
                                                         const int* __restrict__ bbase,
                                                         int2* __restrict__ binned,
                                                         int e, int nblk, int nbuck) {
  __shared__ int cur[256];
  int t = threadIdx.x, blk = blockIdx.x;
  for (int b = t; b < nbuck; b += 256) cur[b] = counts[b * nblk + blk] + bbase[b];
  __syncthreads();
  int base = blk * 4096;
#pragma unroll
  for (int k = 0; k < 16; ++k) {
    int i = base + k * 256 + t;
    if (i < e) {
      int d = dst[i];
      int pos = atomicAdd(&cur[d >> 8], 1);
      binned[pos] = make_int2(src[i], d);
    }
  }
}

__global__ __launch_bounds__(256) void bucket_finalize_kernel(const int2* __restrict__ binned,
                                                              const int* __restrict__ bbase,
                                                              int* __restrict__ offsets,
                                                              int* __restrict__ csr,
                                                              float* __restrict__ dinv,
                                                              int n, int e, int nbuck) {
  __shared__ int deg[256];
  __shared__ int offs[256];
  __shared__ int cur[256];
  int b = blockIdx.x, t = threadIdx.x;
  int ebeg = bbase[b];
  int eend = bbase[b + 1];
  deg[t] = 0;
  __syncthreads();
  for (int j = ebeg + t; j < eend; j += 256) atomicAdd(&deg[binned[j].y & 255], 1);
  __syncthreads();
  int v = deg[t];
  offs[t] = v;
  __syncthreads();
  for (int off = 1; off < 256; off <<= 1) {
    int add = (t >= off) ? offs[t - off] : 0;
    __syncthreads();
    offs[t] += add;
    __syncthreads();
  }
  int excl = offs[t] - v;
  cur[t] = excl;
  int node = b * 256 + t;
  if (node < n) {
    offsets[node] = ebeg + excl;
    float d = (float)(v > 1 ? v : 1);
    dinv[node] = rsqrtf(d);
  }
  if (b == nbuck - 1 && t == 0) offsets[n] = e;
  __syncthreads();
  for (int j = ebeg + t; j < eend; j += 256) {
    int2 pr = binned[j];
    int pos = atomicAdd(&cur[pr.y & 255], 1);
    csr[ebeg + pos] = pr.x;
  }
}

// ---------------- scale16: out16[r][c] = fp16(x[r][c] * dinv[r]) ----------------
__global__ void scale16_kernel(const float* __restrict__ x, const float* __restrict__ dinv,
                               _Float16* __restrict__ out16, int n) {
  int i = blockIdx.x * 256 + threadIdx.x;   // float4 index, 32 per row
  if (i < n * (NF / 4)) {
    int row = i >> 5;
    float4 v = ((const float4*)x)[i];
    float d = dinv[row];
    half4 h;
    h[0] = (_Float16)(v.x * d); h[1] = (_Float16)(v.y * d);
    h[2] = (_Float16)(v.z * d); h[3] = (_Float16)(v.w * d);
    ((half4*)out16)[i] = h;
  }
}

// ---------------- SpMV (fp16 pre-scaled gather source) ----------------
__global__ __launch_bounds__(256) void spmv_kernel(
    const _Float16* __restrict__ xs16, const float* __restrict__ dinv,
    const int* __restrict__ offsets, const int* __restrict__ csr,
    const float* __restrict__ z, float a, float bz,
    float* __restrict__ out, _Float16* __restrict__ outs16, int n) {
  int w = threadIdx.x >> 6, lane = threadIdx.x & 63;
  int node = blockIdx.x * 4 + w;
  if (node >= n) return;
  int beg = __builtin_amdgcn_readfirstlane(offsets[node]);
  int end = __builtin_amdgcn_readfirstlane(offsets[node + 1]);
  int eh = lane >> 4;        // which edge of the quad (0..3)
  int cq = lane & 15;        // half8 slot within the 128-half row

  float acc[8];
#pragma unroll
  for (int j = 0; j < 8; ++j) acc[j] = 0.f;

  int e2 = beg;
  for (; e2 + 8 <= end; e2 += 8) {
    int s0 = csr[e2 + eh];
    int s1 = csr[e2 + 4 + eh];
    half8 g0 = ((const half8*)(xs16 + (size_t)s0 * NF))[cq];
    half8 g1 = ((const half8*)(xs16 + (size_t)s1 * NF))[cq];
#pragma unroll
    for (int j = 0; j < 8; ++j) acc[j] += (float)g0[j];
#pragma unroll
    for (int j = 0; j < 8; ++j) acc[j] += (float)g1[j];
  }
  for (; e2 + 4 <= end; e2 += 4) {
    int s0 = csr[e2 + eh];
    half8 g0 = ((const half8*)(xs16 + (size_t)s0 * NF))[cq];
#pragma unroll
    for (int j = 0; j < 8; ++j) acc[j] += (float)g0[j];
  }
  int rem = end - e2;
  if (eh < rem) {
    int s0 = csr[e2 + eh];
    half8 g0 = ((const half8*)(xs16 + (size_t)s0 * NF))[cq];
#pragma unroll
    for (int j = 0; j < 8; ++j) acc[j] += (float)g0[j];
  }
#pragma unroll
  for (int j = 0; j < 8; ++j) {
    acc[j] += __shfl_xor(acc[j], 16);
    acc[j] += __shfl_xor(acc[j], 32);
  }
  if (eh == 0) {
    float dv = dinv[node];
    float v[8];
#pragma unroll
    for (int j = 0; j < 8; ++j) v[j] = a * dv * acc[j];
    if (z) {
      const f32x4* zp = (const f32x4*)(z + (size_t)node * NF + cq * 8);
      f32x4 z0 = zp[0], z1 = zp[1];
#pragma unroll
      for (int j = 0; j < 4; ++j) { v[j] += bz * z0[j]; v[4 + j] += bz * z1[j]; }
    }
    f32x4 o0, o1;
#pragma unroll
    for (int j = 0; j < 4; ++j) { o0[j] = v[j]; o1[j] = v[4 + j]; }
    f32x4* op = (f32x4*)(out + (size_t)node * NF + cq * 8);
    op[0] = o0; op[1] = o1;
    if (outs16) {
      half8 hv;
#pragma unroll
      for (int j = 0; j < 8; ++j) hv[j] = (_Float16)(v[j] * dv);
      *(half8*)(outs16 + (size_t)node * NF + cq * 8) = hv;
    }
  }
}

// ---------------- W pre-split + frag-pack ----------------
__device__ __forceinline__ void pack_one(const float* __restrict__ W, ushort8* __restrict__ Wp,
                                         int f, int NT, int K) {
  int lane = f & 63;
  int hl = (f >> 6) & 1;
  int rest = f >> 7;
  int nt = rest % NT;
  int kunit = rest / NT;
  int nrow = nt * 16 + (lane & 15);
  int k0 = kunit * 32 + (lane >> 4) * 8;
  const float* srcp = W + (size_t)nrow * K + k0;
  ushort8 v;
#pragma unroll
  for (int j = 0; j < 8; ++j) {
    float x = srcp[j];
    __bf16 h = (__bf16)x;
    if (hl) h = (__bf16)(x - (float)h);
    v[j] = __builtin_bit_cast(unsigned short, h);
  }
  Wp[f] = v;
}

__global__ void pack_all_kernel(const float* __restrict__ W1, ushort8* __restrict__ P1,
                                const float* __restrict__ W3, ushort8* __restrict__ P3,
                                const float* __restrict__ Wm1, ushort8* __restrict__ PM1,
                                const float* __restrict__ Wm2, ushort8* __restrict__ PM2) {
  int f = blockIdx.x * 256 + threadIdx.x;
  if (f < 12288) pack_one(W1, P1, f, 8, 384);
  else if (f < 24576) pack_one(W3, P3, f - 12288, 8, 384);
  else if (f < 28672) pack_one(Wm1, PM1, f - 24576, 8, 128);
  else if (f < 30720) pack_one(Wm2, PM2, f - 28672, 4, 128);
}

// ================= split-bf16 MFMA GEMM machinery =================
// 512-thread blocks: 8 waves (wm in {0,1} x wn in {0..3}); tile 64 rows x NC cols;
// wave tile 32 rows x NC/4 cols. LDS A: [64 rows][16 frags] bf16x8, XOR-swizzled.

__device__ __forceinline__ void lds_put_split(unsigned short* AH, unsigned short* AL,
                                              int row, int col, float v) {
  __bf16 hh = (__bf16)v;
  __bf16 ll = (__bf16)(v - (float)hh);
  int off = row * 128 + ((((col >> 3) ^ (row & 15))) << 3) + (col & 7);
  AH[off] = __builtin_bit_cast(unsigned short, hh);
  AL[off] = __builtin_bit_cast(unsigned short, ll);
}

__device__ __forceinline__ void cvt_frag(const float4& a, const float4& b,
                                         float4* AHI, float4* ALO, int idx) {
  float xv[8] = {a.x, a.y, a.z, a.w, b.x, b.y, b.z, b.w};
  ushort8 hi, lo;
#pragma unroll
  for (int j = 0; j < 8; ++j) {
    __bf16 hh = (__bf16)xv[j];
    __bf16 ll = (__bf16)(xv[j] - (float)hh);
    hi[j] = __builtin_bit_cast(unsigned short, hh);
    lo[j] = __builtin_bit_cast(unsigned short, ll);
  }
  AHI[idx] = __builtin_bit_cast(float4, hi);
  ALO[idx] = __builtin_bit_cast(float4, lo);
}

// wave computes 2 m-frags x NT2 n-frags at one 32-k unit (3 split-bf16 MFMAs per pair)
template<int NT, int NT2>
__device__ __forceinline__ void gemm_step512(const float4* AHI, const float4* ALO,
                                             const ushort8* __restrict__ Wp, int kunit,
                                             int lane, int wm, int wn, f32x4 (*acc)[NT2]) {
  bf16x8 ah[2], al[2];
#pragma unroll
  for (int mt = 0; mt < 2; ++mt) {
    int arow = wm * 32 + mt * 16 + (lane & 15);
    int fc = (kunit & 3) * 4 + (lane >> 4);
    int idx = arow * 16 + (fc ^ (arow & 15));
    ah[mt] = __builtin_bit_cast(bf16x8, AHI[idx]);
    al[mt] = __builtin_bit_cast(bf16x8, ALO[idx]);
  }
#pragma unroll
  for (int j = 0; j < NT2; ++j) {
    int nt = wn * NT2 + j;
    const ushort8* bp = Wp + (size_t)(kunit * NT + nt) * 2 * 64 + lane;
    bf16x8 bh = __builtin_bit_cast(bf16x8, bp[0]);
    bf16x8 bl = __builtin_bit_cast(bf16x8, bp[64]);
#pragma unroll
    for (int mt = 0; mt < 2; ++mt) {
      acc[mt][j] = __builtin_amdgcn_mfma_f32_16x16x32_bf16(ah[mt], bh, acc[mt][j], 0, 0, 0);
      acc[mt][j] = __builtin_amdgcn_mfma_f32_16x16x32_bf16(ah[mt], bl, acc[mt][j], 0, 0, 0);
      acc[mt][j] = __builtin_amdgcn_mfma_f32_16x16x32_bf16(al[mt], bh, acc[mt][j], 0, 0, 0);
    }
  }
}

// ---------------- conv1 GEMM + fused BN partial stats ----------------
__global__ __launch_bounds__(512) void conv1_gemm_kernel(
    const float* __restrict__ X0, const float* __restrict__ X1, const float* __restrict__ X2,
    const ushort8* __restrict__ Wp, const float* __restrict__ bias,
    float* __restrict__ out, float* __restrict__ stats, int n) {
  __shared__ float4 AHI[1024];   // 64 rows x 16 frags
  __shared__ float4 ALO[1024];
  __shared__ float sstat[256];

  int tid = threadIdx.x;
  int lane = tid & 63, wid = tid >> 6;
  int wm = wid >> 2, wn = wid & 3;
  int r0 = blockIdx.x * 64;

  f32x4 acc[2][2];
#pragma unroll
  for (int mt = 0; mt < 2; ++mt)
#pragma unroll
    for (int j = 0; j < 2; ++j) acc[mt][j] = (f32x4)0.f;

  const float* Xarr[3] = {X0, X1, X2};
  float4 pa0[2], pa1[2];
#pragma unroll
  for (int h = 0; h < 2; ++h) {
    int f = tid + h * 512, row = f >> 4, fc = f & 15, grow = r0 + row;
    float4 z = make_float4(0.f, 0.f, 0.f, 0.f);
    pa0[h] = z; pa1[h] = z;
    if (grow < n) {
      const float4* s = (const float4*)(X0 + (size_t)grow * NF + fc * 8);
      pa0[h] = s[0]; pa1[h] = s[1];
    }
  }
#pragma unroll
  for (int p = 0; p < 3; ++p) {
#pragma unroll
    for (int h = 0; h < 2; ++h) {
      int f = tid + h * 512, row = f >> 4, fc = f & 15;
      cvt_frag(pa0[h], pa1[h], AHI, ALO, row * 16 + (fc ^ (row & 15)));
    }
    if (p + 1 < 3) {
      const float* Xn = Xarr[p + 1];
#pragma unroll
      for (int h = 0; h < 2; ++h) {
        int f = tid + h * 512, row = f >> 4, fc = f & 15, grow = r0 + row;
        if (grow < n) {
          const float4* s = (const float4*)(Xn + (size_t)grow * NF + fc * 8);
          pa0[h] = s[0]; pa1[h] = s[1];
        }
      }
    }
    __syncthreads();
#pragma unroll
    for (int ks = 0; ks < 4; ++ks)
      gemm_step512<8, 2>(AHI, ALO, Wp, p * 4 + ks, lane, wm, wn, acc);
    __syncthreads();
  }
  // epilogue: relu + store + BN partial stats
  if (tid < 256) sstat[tid] = 0.f;
  __syncthreads();
#pragma unroll
  for (int mt = 0; mt < 2; ++mt) {
    int rbase = r0 + wm * 32 + mt * 16 + (lane >> 4) * 4;
#pragma unroll
    for (int j = 0; j < 2; ++j) {
      int col = wn * 32 + j * 16 + (lane & 15);
      float b = bias[col];
      float sj = 0.f, qj = 0.f;
#pragma unroll
      for (int i = 0; i < 4; ++i) {
        int row = rbase + i;
        if (row < n) {
          float v = fmaxf(acc[mt][j][i] + b, 0.f);
          out[(size_t)row * NF + col] = v;
          sj += v; qj += v * v;
        }
      }
      sj += __shfl_xor(sj, 16); sj += __shfl_xor(sj, 32);
      qj += __shfl_xor(qj, 16); qj += __shfl_xor(qj, 32);
      if ((lane >> 4) == 0) {
        atomicAdd(&sstat[col], sj);
        atomicAdd(&sstat[128 + col], qj);
      }
    }
  }
  __syncthreads();
  if (tid < 256) atomicAdd(&stats[tid], sstat[tid]);
}

// ---------------- fused tail: Y = relu([X,T1,T2]@W3^T+b3)+X ; H = relu(Y@Wm1^T+bm1);
//                  out = H@Wm2^T+bm2.  Y and H never leave the chip. ----------------
__global__ __launch_bounds__(512) void fused_tail_kernel(
    const float* __restrict__ X, const float* __restrict__ T1, const float* __restrict__ T2,
    const ushort8* __restrict__ Wp3, const float* __restrict__ b3,
    const ushort8* __restrict__ WpM1, const float* __restrict__ bm1,
    const ushort8* __restrict__ WpM2, const float* __restrict__ bm2,
    float* __restrict__ out, int n) {
  __shared__ float4 AHI[1024];
  __shared__ float4 ALO[1024];
  unsigned short* AHu = (unsigned short*)AHI;
  unsigned short* ALu = (unsigned short*)ALO;

  int tid = threadIdx.x;
  int lane = tid & 63, wid = tid >> 6;
  int wm = wid >> 2, wn = wid & 3;
  int r0 = blockIdx.x * 64;

  f32x4 acc[2][2];
#pragma unroll
  for (int mt = 0; mt < 2; ++mt)
#pragma unroll
    for (int j = 0; j < 2; ++j) acc[mt][j] = (f32x4)0.f;

  // ---- phase 1: conv2 GEMM over parts {X, T1, T2}
  const float* Xarr[3] = {X, T1, T2};
  float4 pa0[2], pa1[2];
#pragma unroll
  for (int h = 0; h < 2; ++h) {
    int f = tid + h * 512, row = f >> 4, fc = f & 15, grow = r0 + row;
    float4 z = make_float4(0.f, 0.f, 0.f, 0.f);
    pa0[h] = z; pa1[h] = z;
    if (grow < n) {
      const float4* s = (const float4*)(X + (size_t)grow * NF + fc * 8);
      pa0[h] = s[0]; pa1[h] = s[1];
    }
  }
#pragma unroll
  for (int p = 0; p < 3; ++p) {
#pragma unroll
    for (int h = 0; h < 2; ++h) {
      int f = tid + h * 512, row = f >> 4, fc = f & 15;
      cvt_frag(pa0[h], pa1[h], AHI, ALO, row * 16 + (fc ^ (row & 15)));
    }
    if (p + 1 < 3) {
      const float* Xn = Xarr[p + 1];
#pragma unroll
      for (int h = 0; h < 2; ++h) {
        int f = tid + h * 512, row = f >> 4, fc = f & 15, grow = r0 + row;
        if (grow < n) {
          const float4* s = (const float4*)(Xn + (size_t)grow * NF + fc * 8);
          pa0[h] = s[0]; pa1[h] = s[1];
        }
      }
    }
    __syncthreads();
#pragma unroll
    for (int ks = 0; ks < 4; ++ks)
      gemm_step512<8, 2>(AHI, ALO, Wp3, p * 4 + ks, lane, wm, wn, acc);
    __syncthreads();
  }
  // ---- epilogue 1: Y = relu(acc+b3)+X, scatter-convert into LDS A-layout
#pragma unroll
  for (int mt = 0; mt < 2; ++mt) {
    int rb = wm * 32 + mt * 16 + (lane >> 4) * 4;
#pragma unroll
    for (int j = 0; j < 2; ++j) {
      int col = wn * 32 + j * 16 + (lane & 15);
      float b = b3[col];
#pragma unroll
      for (int i = 0; i < 4; ++i) {
        int lrow = rb + i;
        int row = r0 + lrow;
        float v = 0.f;
        if (row < n) v = fmaxf(acc[mt][j][i] + b, 0.f) + X[(size_t)row * NF + col];
        lds_put_split(AHu, ALu, lrow, col, v);
      }
    }
  }
  __syncthreads();
  // ---- phase 2: H = relu(Y @ Wm1^T + bm1)
  f32x4 acc2[2][2];
#pragma unroll
  for (int mt = 0; mt < 2; ++mt)
#pragma unroll
    for (int j = 0; j < 2; ++j) acc2[mt][j] = (f32x4)0.f;
#pragma unroll
  for (int ks = 0; ks < 4; ++ks)
    gemm_step512<8, 2>(AHI, ALO, WpM1, ks, lane, wm, wn, acc2);
  __syncthreads();   // all reads of Y done before overwrite
  // ---- epilogue 2: scatter H into LDS A-layout
#pragma unroll
  for (int mt = 0; mt < 2; ++mt) {
    int rb = wm * 32 + mt * 16 + (lane >> 4) * 4;
#pragma unroll
    for (int j = 0; j < 2; ++j) {
      int col = wn * 32 + j * 16 + (lane & 15);
      float b = bm1[col];
#pragma unroll
      for (int i = 0; i < 4; ++i) {
        float v = fmaxf(acc2[mt][j][i] + b, 0.f);
        lds_put_split(AHu, ALu, rb + i, col, v);
      }
    }
  }
  __syncthreads();
  // ---- phase 3: out = H @ Wm2^T + bm2   (NC=64 -> NT=4, NT2=1 per wave)
  f32x4 acc3[2][1];
#pragma unroll
  for (int mt = 0; mt < 2; ++mt) acc3[mt][0] = (f32x4)0.f;
#pragma unroll
  for (int ks = 0; ks < 4; ++ks)
    gemm_step512<4, 1>(AHI, ALO, WpM2, ks, lane, wm, wn, acc3);
  // ---- epilogue 3: write final output (N x 64)
#pragma unroll
  for (int mt = 0; mt < 2; ++mt) {
    int rb = wm * 32 + mt * 16 + (lane >> 4) * 4;
    int col = wn * 16 + (lane & 15);
    float b = bm2[col];
#pragma unroll
    for (int i = 0; i < 4; ++i) {
      int row = r0 + rb + i;
      if (row < n) out[(size_t)row * 64 + col] = acc3[mt][0][i] + b;
    }
  }
}

// ---------------- BatchNorm scale/apply ----------------
__global__ void bn_scale_kernel(const float* __restrict__ stats, const float* __restrict__ gamma,
                                const float* __restrict__ beta, float* __restrict__ sc,
                                float* __restrict__ sh, float n) {
  int c = threadIdx.x;   // 128
  float mu = stats[c] / n;
  float var = stats[NF + c] / n - mu * mu;
  float s = gamma[c] * rsqrtf(var + 1e-5f);
  sc[c] = s;
  sh[c] = beta[c] - mu * s;
}

__global__ void bn_apply_kernel(float* __restrict__ x, const float* __restrict__ sc,
                                const float* __restrict__ sh, const float* __restrict__ dinv,
                                _Float16* __restrict__ xs16, int n) {
  int i = blockIdx.x * 256 + threadIdx.x;   // float4 index
  if (i < n * (NF / 4)) {
    int row = i >> 5;
    int c0 = (i & 31) * 4;
    float4 v = ((const float4*)x)[i];
    v.x = v.x * sc[c0 + 0] + sh[c0 + 0];
    v.y = v.y * sc[c0 + 1] + sh[c0 + 1];
    v.z = v.z * sc[c0 + 2] + sh[c0 + 2];
    v.w = v.w * sc[c0 + 3] + sh[c0 + 3];
    ((float4*)x)[i] = v;
    float d = dinv[row];
    half4 h;
    h[0] = (_Float16)(v.x * d); h[1] = (_Float16)(v.y * d);
    h[2] = (_Float16)(v.z * d); h[3] = (_Float16)(v.w * d);
    ((half4*)xs16)[i] = h;
  }
}

// ---------------- launcher ----------------
extern "C" void kernel_launch(void* const* d_in, const int* in_sizes, int n_in,
                              void* d_out, int out_size, void* d_ws, size_t ws_size,
                              hipStream_t stream) {
  const float* feat  = (const float*)d_in[0];
  const int*   src   = (const int*)d_in[1];
  const int*   dst   = (const int*)d_in[2];
  const float* W1    = (const float*)d_in[3];
  const float* b1    = (const float*)d_in[4];
  const float* W3    = (const float*)d_in[5];
  const float* b3    = (const float*)d_in[6];
  const float* gamma = (const float*)d_in[7];
  const float* beta  = (const float*)d_in[8];
  const float* Wm1   = (const float*)d_in[9];
  const float* bm1   = (const float*)d_in[10];
  const float* Wm2   = (const float*)d_in[11];
  const float* bm2   = (const float*)d_in[12];
  int n = in_sizes[0] / NF;
  int e = in_sizes[1];

  char* p = (char*)d_ws;
  auto alloc = [&](size_t bytes) {
    char* r = p;
    p += (bytes + 255) & ~size_t(255);
    return r;
  };
  int nblk  = ceil_div(e, 4096);   // multisplit tiles
  int nbuck = ceil_div(n, 256);    // node buckets

  float* dinv     = (float*)alloc((size_t)n * 4);
  int*   offsets  = (int*)alloc((size_t)(n + 1) * 4);
  int*   counts   = (int*)alloc((size_t)nblk * nbuck * 4);
  int*   btot     = (int*)alloc((size_t)nbuck * 4);
  int*   bbase    = (int*)alloc((size_t)(nbuck + 1) * 4);
  int*   csr      = (int*)alloc((size_t)e * 4);
  float* stats    = (float*)alloc(256 * 4);
  float* bnsc     = (float*)alloc(128 * 4);
  float* bnsh     = (float*)alloc(128 * 4);
  ushort8* Wp1  = (ushort8*)alloc(12 * 8 * 2 * 64 * 16);   // K=384, NT=8
  ushort8* Wp3  = (ushort8*)alloc(12 * 8 * 2 * 64 * 16);
  ushort8* WpM1 = (ushort8*)alloc(4 * 8 * 2 * 64 * 16);    // K=128, NT=8
  ushort8* WpM2 = (ushort8*)alloc(4 * 4 * 2 * 64 * 16);    // K=128, NT=4
  size_t matb = (size_t)n * NF * 4;
  float* T1 = (float*)alloc(matb);
  float* T2 = (float*)alloc(matb);
  float* X  = (float*)alloc(matb);   // conv1 out -> BN in place -> x_res
  _Float16* xsA  = (_Float16*)alloc((size_t)n * NF * 2);  // Fs16 then Xs16
  _Float16* xsB  = (_Float16*)alloc((size_t)n * NF * 2);  // T1s16 (both convs)
  int2* binned = (int2*)T2;          // alias: 6.4MB scratch, dead before spmv writes T2

  hipMemsetAsync(stats, 0, 256 * 4, stream);

  int fb = ceil_div(n * (NF / 4), 256);      // float4-grid over matrices
  int sb = ceil_div(n, 4);                   // spmv: 4 nodes/block
  int gb = ceil_div(n, 64);                  // gemm: 64 rows/block, 512 threads

  // CSR build (sorted by dst) via two-level multisplit; also emits offsets/dinv
  bucket_hist_kernel<<<nblk, 256, 0, stream>>>(dst, counts, e, nblk, nbuck);
  bucket_scan_rows_kernel<<<nbuck, 256, 0, stream>>>(counts, btot, nblk);
  bucket_base_kernel<<<1, 256, 0, stream>>>(btot, bbase, nbuck, e);
  bucket_bin_kernel<<<nblk, 256, 0, stream>>>(src, dst, counts, bbase, binned, e, nblk, nbuck);
  bucket_finalize_kernel<<<nbuck, 256, 0, stream>>>(binned, bbase, offsets, csr, dinv, n, e, nbuck);

  // W split+pack (one launch)
  pack_all_kernel<<<120, 256, 0, stream>>>(W1, Wp1, W3, Wp3, Wm1, WpM1, Wm2, WpM2);

  // conv1: T1 = -A^ F ; T2 = -2 A^ T1 - F ; X = relu([F,T1,T2] @ W1^T + b1)  (+BN stats)
  scale16_kernel<<<fb, 256, 0, stream>>>(feat, dinv, xsA, n);
  spmv_kernel<<<sb, 256, 0, stream>>>(xsA, dinv, offsets, csr, nullptr, -1.f, 0.f, T1, xsB, n);
  spmv_kernel<<<sb, 256, 0, stream>>>(xsB, dinv, offsets, csr, feat, -2.f, -1.f, T2, nullptr, n);
  conv1_gemm_kernel<<<gb, 512, 0, stream>>>(feat, T1, T2, Wp1, b1, X, stats, n);

  // BatchNorm finalize + apply in place; X becomes x_res; xsA = fp16(X*dinv)
  bn_scale_kernel<<<1, 128, 0, stream>>>(stats, gamma, beta, bnsc, bnsh, (float)n);
  bn_apply_kernel<<<fb, 256, 0, stream>>>(X, bnsc, bnsh, dinv, xsA, n);

  // conv2 spmvs
  spmv_kernel<<<sb, 256, 0, stream>>>(xsA, dinv, offsets, csr, nullptr, -1.f, 0.f, T1, xsB, n);
  spmv_kernel<<<sb, 256, 0, stream>>>(xsB, dinv, offsets, csr, X, -2.f, -1.f, T2, nullptr, n);

  // fused conv2-GEMM + residual + MLP1 + MLP2 (Y, H stay on-chip)
  fused_tail_kernel<<<gb, 512, 0, stream>>>(X, T1, T2, Wp3, b3, WpM1, bm1, WpM2, bm2,
                                            (float*)d_out, n);
}